// Round 21
// baseline (26.542 us; speedup 1.0000x reference)
//
#include <hip/hip_runtime.h>
#include <hip/hip_bf16.h>

// AWQ 4-bit linear: out[32,11008] = x[32,4096] @ ((q - z)*s) + bias
// Round 21: IN-BLOCK K-PAIR SUM. Block = 128 cols x 2 kchunks (waves 0-1:
// k-half 0 stripes 0/1; waves 2-3: k-half 1). Per-wave program = R20
// verbatim (64 cols x 256 k, pipelined, q-hoist, swizzled per-wave LDS,
// barrier-free loop). After the loop, k-half-1 waves push acc through
// lds[0] (idx-major, conflict-free; tile 7 only touched lds[1]) and
// k-half-0 waves sum -> 8 bf16 slabs instead of 16: reduce traffic
// 11.25 -> 5.6 MB. NBLK stays 688 (best dispatch shape).

#define IN_F   4096
#define OUT_F  11008
#define WCOLS  1376
#define NCOLB  86                 // 128-col regions
#define NKC    8                  // slab k-regions (2 kchunks each)
#define CHUNK  256                // k per wave
#define NTILE  (CHUNK/32)         // 8
#define NBLK   (NCOLB*NKC)        // 688 = 8*86
#define MROWS  32
#define SLAB   (MROWS*OUT_F)      // elements per k-partial slab (352256)

typedef __attribute__((ext_vector_type(8))) short  short8;
typedef __attribute__((ext_vector_type(4))) unsigned short ushort4v;
typedef __attribute__((ext_vector_type(4))) float  f32x4;
typedef __attribute__((ext_vector_type(4))) int    int4v;

__device__ __forceinline__ short f2bf(float f) {
  return (short)__builtin_bit_cast(unsigned short, (__bf16)f);
}
__device__ __forceinline__ unsigned short f2bfu(float f) {
  return __builtin_bit_cast(unsigned short, (__bf16)f);
}
__device__ __forceinline__ float bf2f(unsigned short u) {
  return __builtin_bit_cast(float, ((unsigned int)u) << 16);
}
__device__ __forceinline__ f32x4 mfma16(short8 a, short8 b, f32x4 c) {
  return __builtin_amdgcn_mfma_f32_16x16x32_bf16(a, b, c, 0, 0, 0);
}

__global__ void awq_init(const float* __restrict__ bias, float* __restrict__ out) {
  int o = blockIdx.x * 256 + threadIdx.x;
  out[blockIdx.y * OUT_F + o] = bias[o];
}

__global__ __launch_bounds__(256) void awq_reduce(
    const unsigned short* __restrict__ ws, const float* __restrict__ bias,
    float* __restrict__ out)
{
  const int i = blockIdx.x * 256 + threadIdx.x;    // 4-col id, 88064 total
  f32x4 s = *(const f32x4*)(bias + (i % (OUT_F / 4)) * 4);
  const ushort4v* w4 = (const ushort4v*)ws;
  #pragma unroll
  for (int k = 0; k < NKC; ++k) {
    ushort4v v = __builtin_nontemporal_load(&w4[k * (SLAB / 4) + i]);
    #pragma unroll
    for (int j = 0; j < 4; ++j) s[j] += bf2f(v[j]);
  }
  ((f32x4*)out)[i] = s;
}

template<bool TOWS>
__global__ __launch_bounds__(256, 3) void awq_main(
    const float* __restrict__ x,
    const int* __restrict__ qw, const int* __restrict__ qz,
    const float* __restrict__ sc, void* __restrict__ outp)
{
  // Per-wave, per-half private staging: [buf][wave][half][512 dw] = 32 KB.
  // lds[0] (16 KB) doubles as the end-of-kernel acc-exchange buffer.
  __shared__ int lds[2][4][2][512];

  const int tid  = threadIdx.x;
  const int w    = tid >> 6;           // wave 0..3
  const int wk   = w & 1;              // 64-col stripe within 128-col region
  const int kh   = w >> 1;             // k-half 0/1
  const int lane = tid & 63;
  const int q4   = lane >> 4;          // MFMA k-octet
  const int cl   = lane & 15;          // MFMA col-in-frag
  const int ww   = lane & 3;           // dequant: word -> cols 8ww..8ww+7
  const int kp2  = lane >> 2;          // dequant: k-pair 0..15
  const int kps  = kp2 ^ (ww << 2);    // swizzled k-pair slot (verified)

  // Bijective XCD swizzle (688 = 8*86)
  const int b  = blockIdx.x;
  const int L  = (b & 7) * (NBLK / 8) + (b >> 3);
  const int colb = L % NCOLB;
  const int kc   = L / NCOLB;          // slab k-region 0..7

  const int kchunk = kc * 2 + kh;      // 0..15
  const int cb  = colb * 128;          // first output column of region
  const int wcb = colb * 16;           // first packed word of region
  const int K0  = kchunk * CHUNK;
  const int g0  = kchunk * (CHUNK / 128);   // 2 groups per chunk
  const int cw  = cb + wk * 64;        // wave's first column
  const int wqw = wcb + wk * 8;        // wave's first packed word

  // group scale/zero per half: raw staging -> converted s8/zs8
  f32x4 sra[2], srb[2]; int zrw[2];
  float s8[2][8], zs8[2][8];
  auto load_group_raw = [&](int g) {
    #pragma unroll
    for (int h = 0; h < 2; ++h) {
      sra[h] = *(const f32x4*)(sc + g * OUT_F + cw + h * 32 + ww * 8);
      srb[h] = *(const f32x4*)(sc + g * OUT_F + cw + h * 32 + ww * 8 + 4);
      zrw[h] = qz[g * WCOLS + wqw + h * 4 + ww];
    }
  };
  auto conv_group = [&]() {
    #pragma unroll
    for (int h = 0; h < 2; ++h) {
      #pragma unroll
      for (int j = 0; j < 8; ++j) {
        const int sh = 4 * (j >> 1) + 16 * (j & 1);   // shift = 4*REV[j]
        const float sv = (j < 4) ? sra[h][j] : srb[h][j - 4];
        s8[h][j]  = sv;
        zs8[h][j] = -(float)((zrw[h] >> sh) & 15) * sv;
      }
    }
  };
  auto load_a = [&](int t, int mf) -> short8 {
    const int m = cl + 16 * mf;
    const int k = K0 + t * 32 + q4 * 8;
    const f32x4* xp = (const f32x4*)(x + m * IN_F + k);
    f32x4 lo = xp[0], hi = xp[1];
    short8 af;
    #pragma unroll
    for (int j = 0; j < 4; ++j) { af[j] = f2bf(lo[j]); af[4 + j] = f2bf(hi[j]); }
    return af;
  };
  // read (col c, kp=4q4+i) stored at c*16 + (kp ^ ((c>>3)<<2)):
  // b128 at c*16 + 4*(q4 ^ ((c>>3)&3)) -> k-contiguous 8q4..8q4+7.
  auto read_b = [&](int p, int h, int c) -> short8 {
    const int idx = c * 16 + 4 * (q4 ^ ((c >> 3) & 3));
    return __builtin_bit_cast(short8, *(const int4v*)&lds[p][w][h][idx]);
  };

  // ---- prologue: group-0 raws, ALL q-loads (8 tiles x 2 halves) to regs.
  load_group_raw(g0);
  int qa[NTILE][2], qb[NTILE][2];
  #pragma unroll
  for (int t = 0; t < NTILE; ++t) {
    #pragma unroll
    for (int h = 0; h < 2; ++h) {
      const int r = (K0 + t * 32 + 2 * kp2) * WCOLS + wqw + h * 4 + ww;
      qa[t][h] = qw[r];
      qb[t][h] = qw[r + WCOLS];
    }
  }
  conv_group();
  f32x4 acc[2][2][2] = {};   // [mf][h][cfrag]

  // dequant + LDS-write for tile t (p = t&1 static under full unroll)
  auto dq_write = [&](int t) {
    const int p = t & 1;
    #pragma unroll
    for (int h = 0; h < 2; ++h) {
      #pragma unroll
      for (int j = 0; j < 8; ++j) {
        const int sh = 4 * (j >> 1) + 16 * (j & 1);
        const float lo = fmaf((float)((qa[t][h] >> sh) & 15), s8[h][j], zs8[h][j]);
        const float hi = fmaf((float)((qb[t][h] >> sh) & 15), s8[h][j], zs8[h][j]);
        const unsigned int pk =
            (unsigned int)(unsigned short)f2bf(lo) |
            ((unsigned int)(unsigned short)f2bf(hi) << 16);
        lds[p][w][h][(ww * 8 + j) * 16 + kps] = (int)pk;
      }
    }
  };

  // ---- pipelined main loop: write(t) while consuming (t-1)
  dq_write(0);
  short8 a0c = load_a(0, 0), a1c = load_a(0, 1);

  #pragma unroll
  for (int t = 1; t < NTILE; ++t) {
    const int pm = (t - 1) & 1;
    short8 bf00 = read_b(pm, 0, cl), bf01 = read_b(pm, 0, cl + 16);
    short8 bf10 = read_b(pm, 1, cl), bf11 = read_b(pm, 1, cl + 16);
    short8 a0n = load_a(t, 0), a1n = load_a(t, 1);
    if (t == 2) load_group_raw(g0 + 1);   // raws 2 tiles early
    if (t == 4) conv_group();             // group 1 live for tiles 4..7

    dq_write(t);                          // VALU hides the reads above

    acc[0][0][0] = mfma16(a0c, bf00, acc[0][0][0]);
    acc[0][0][1] = mfma16(a0c, bf01, acc[0][0][1]);
    acc[1][0][0] = mfma16(a1c, bf00, acc[1][0][0]);
    acc[1][0][1] = mfma16(a1c, bf01, acc[1][0][1]);
    acc[0][1][0] = mfma16(a0c, bf10, acc[0][1][0]);
    acc[0][1][1] = mfma16(a0c, bf11, acc[0][1][1]);
    acc[1][1][0] = mfma16(a1c, bf10, acc[1][1][0]);
    acc[1][1][1] = mfma16(a1c, bf11, acc[1][1][1]);

    a0c = a0n; a1c = a1n;
  }

  // ---- final tile (reads from lds[1] only: pm = 7&1 = 1)
  {
    const int pm = (NTILE - 1) & 1;
    short8 bf00 = read_b(pm, 0, cl), bf01 = read_b(pm, 0, cl + 16);
    short8 bf10 = read_b(pm, 1, cl), bf11 = read_b(pm, 1, cl + 16);
    acc[0][0][0] = mfma16(a0c, bf00, acc[0][0][0]);
    acc[0][0][1] = mfma16(a0c, bf01, acc[0][0][1]);
    acc[1][0][0] = mfma16(a1c, bf00, acc[1][0][0]);
    acc[1][0][1] = mfma16(a1c, bf01, acc[1][0][1]);
    acc[0][1][0] = mfma16(a0c, bf10, acc[0][1][0]);
    acc[0][1][1] = mfma16(a0c, bf11, acc[0][1][1]);
    acc[1][1][0] = mfma16(a1c, bf10, acc[1][1][0]);
    acc[1][1][1] = mfma16(a1c, bf11, acc[1][1][1]);
  }

  // ---- output epilogue
  const int r0 = q4 * 4;
  if constexpr (TOWS) {
    // in-block k-pair sum through lds[0] (idx-major: conflict-free,
    // no overlap with lds[1], which held the final tile)
    float* xch = (float*)&lds[0][0][0][0];   // 4096 floats = 16 KB
    const int base = wk * 64 + lane;         // 0..127
    __syncthreads();                         // all waves past main loop
    if (kh == 1) {
      #pragma unroll
      for (int mf = 0; mf < 2; ++mf)
        #pragma unroll
        for (int h = 0; h < 2; ++h)
          #pragma unroll
          for (int cf = 0; cf < 2; ++cf)
            #pragma unroll
            for (int i = 0; i < 4; ++i) {
              const int e = (((mf * 2 + h) * 2 + cf) * 4 + i);
              xch[e * 128 + base] = acc[mf][h][cf][i];
            }
    }
    __syncthreads();
    if (kh == 0) {
      unsigned short* wsp = (unsigned short*)outp + kc * SLAB;
      #pragma unroll
      for (int mf = 0; mf < 2; ++mf)
        #pragma unroll
        for (int h = 0; h < 2; ++h)
          #pragma unroll
          for (int cf = 0; cf < 2; ++cf)
            #pragma unroll
            for (int i = 0; i < 4; ++i) {
              const int e = (((mf * 2 + h) * 2 + cf) * 4 + i);
              const float sum = acc[mf][h][cf][i] + xch[e * 128 + base];
              const int row = mf * 16 + r0 + i;
              const int c0  = cw + h * 32 + cl + cf * 16;
              __builtin_nontemporal_store(f2bfu(sum), wsp + row * OUT_F + c0);
            }
    }
  } else {
    // fallback: fp32 atomics onto bias-initialized out
    float* op = (float*)outp;
    #pragma unroll
    for (int mf = 0; mf < 2; ++mf) {
      #pragma unroll
      for (int h = 0; h < 2; ++h) {
        #pragma unroll
        for (int i = 0; i < 4; ++i) {
          const int row = mf * 16 + r0 + i;
          const int c0  = cw + h * 32 + cl;
          atomicAdd(op + row * OUT_F + c0,      acc[mf][h][0][i]);
          atomicAdd(op + row * OUT_F + c0 + 16, acc[mf][h][1][i]);
        }
      }
    }
  }
}

extern "C" void kernel_launch(void* const* d_in, const int* in_sizes, int n_in,
                              void* d_out, int out_size, void* d_ws, size_t ws_size,
                              hipStream_t stream) {
  const float* x    = (const float*)d_in[0];
  const int*   qwp  = (const int*)d_in[1];
  const int*   qzp  = (const int*)d_in[2];
  const float* scp  = (const float*)d_in[3];
  const float* bias = (const float*)d_in[4];
  float* out = (float*)d_out;

  const size_t ws_slabs = (size_t)NKC * SLAB * 2;   // 5.6 MB (bf16)

  if (ws_size >= ws_slabs) {
    unsigned short* ws = (unsigned short*)d_ws;
    awq_main<true><<<NBLK, 256, 0, stream>>>(x, qwp, qzp, scp, ws);
    awq_reduce<<<SLAB / 4 / 256, 256, 0, stream>>>(ws, bias, out);
  } else {
    awq_init<<<dim3(43, 32), 256, 0, stream>>>(bias, out);
    awq_main<false><<<NBLK, 256, 0, stream>>>(x, qwp, qzp, scp, out);
  }
}

// Round 22
// 25.715 us; speedup vs baseline: 1.0322x; 1.0322x over previous
//
#include <hip/hip_runtime.h>
#include <hip/hip_bf16.h>

// AWQ 4-bit linear: out[32,11008] = x[32,4096] @ ((q - z)*s) + bias
// Round 22: SINGLE-VARIABLE on the R21 winner (26.5us): swap bf16 fmaf
// dequant for the fp16 perm-dequant validated in R10-12 (absmax 0.125).
// Mechanism: R20's pipeline put dequant VALU on the per-tile critical
// path (reads hide under it); fp16 path cuts ~12 VALU/2-nibbles to ~5
// (v_perm gather -> and_or 0x6400 bias -> exact pk_add(q-z) -> pk_mul).
// A-loads convert f32->fp16; MFMA f32_16x16x32_f16 (C/D layout
// dtype-independent). Everything else byte-identical to R21: 688 blk,
// 128col x 2kchunk blocks, per-wave swizzled LDS, q-hoist, software
// pipeline, in-block k-pair sum, 8 bf16 nt-slabs + reduce.

#define IN_F   4096
#define OUT_F  11008
#define WCOLS  1376
#define NCOLB  86                 // 128-col regions
#define NKC    8                  // slab k-regions (2 kchunks each)
#define CHUNK  256                // k per wave
#define NTILE  (CHUNK/32)         // 8
#define NBLK   (NCOLB*NKC)        // 688 = 8*86
#define MROWS  32
#define SLAB   (MROWS*OUT_F)      // elements per k-partial slab (352256)

typedef __attribute__((ext_vector_type(2))) _Float16 half2v;
typedef __attribute__((ext_vector_type(8))) _Float16 half8v;
typedef __attribute__((ext_vector_type(4))) unsigned short ushort4v;
typedef __attribute__((ext_vector_type(4))) float  f32x4;
typedef __attribute__((ext_vector_type(4))) int    int4v;

__device__ __forceinline__ unsigned short f2bfu(float f) {
  return __builtin_bit_cast(unsigned short, (__bf16)f);
}
__device__ __forceinline__ float bf2f(unsigned short u) {
  return __builtin_bit_cast(float, ((unsigned int)u) << 16);
}
__device__ __forceinline__ half2v splat_h(float f) {
  unsigned short b = __builtin_bit_cast(unsigned short, (_Float16)f);
  unsigned int u = (unsigned int)b | ((unsigned int)b << 16);
  return __builtin_bit_cast(half2v, u);
}
__device__ __forceinline__ f32x4 mfma16h(half8v a, half8v b, f32x4 c) {
  return __builtin_amdgcn_mfma_f32_16x16x32_f16(a, b, c, 0, 0, 0);
}

__global__ void awq_init(const float* __restrict__ bias, float* __restrict__ out) {
  int o = blockIdx.x * 256 + threadIdx.x;
  out[blockIdx.y * OUT_F + o] = bias[o];
}

__global__ __launch_bounds__(256) void awq_reduce(
    const unsigned short* __restrict__ ws, const float* __restrict__ bias,
    float* __restrict__ out)
{
  const int i = blockIdx.x * 256 + threadIdx.x;    // 4-col id, 88064 total
  f32x4 s = *(const f32x4*)(bias + (i % (OUT_F / 4)) * 4);
  const ushort4v* w4 = (const ushort4v*)ws;
  #pragma unroll
  for (int k = 0; k < NKC; ++k) {
    ushort4v v = __builtin_nontemporal_load(&w4[k * (SLAB / 4) + i]);
    #pragma unroll
    for (int j = 0; j < 4; ++j) s[j] += bf2f(v[j]);
  }
  ((f32x4*)out)[i] = s;
}

template<bool TOWS>
__global__ __launch_bounds__(256, 3) void awq_main(
    const float* __restrict__ x,
    const int* __restrict__ qw, const int* __restrict__ qz,
    const float* __restrict__ sc, void* __restrict__ outp)
{
  // Per-wave, per-half private staging: [buf][wave][half][512 dw] = 32 KB.
  // lds[0] (16 KB) doubles as the end-of-kernel acc-exchange buffer.
  __shared__ int lds[2][4][2][512];

  const int tid  = threadIdx.x;
  const int w    = tid >> 6;           // wave 0..3
  const int wk   = w & 1;              // 64-col stripe within 128-col region
  const int kh   = w >> 1;             // k-half 0/1
  const int lane = tid & 63;
  const int q4   = lane >> 4;          // MFMA k-octet
  const int cl   = lane & 15;          // MFMA col-in-frag
  const int ww   = lane & 3;           // dequant: word -> cols 8ww..8ww+7
  const int kp2  = lane >> 2;          // dequant: k-pair 0..15
  const int kps  = kp2 ^ (ww << 2);    // swizzled k-pair slot (verified)

  // Bijective XCD swizzle (688 = 8*86)
  const int b  = blockIdx.x;
  const int L  = (b & 7) * (NBLK / 8) + (b >> 3);
  const int colb = L % NCOLB;
  const int kc   = L / NCOLB;          // slab k-region 0..7

  const int kchunk = kc * 2 + kh;      // 0..15
  const int cb  = colb * 128;          // first output column of region
  const int wcb = colb * 16;           // first packed word of region
  const int K0  = kchunk * CHUNK;
  const int g0  = kchunk * (CHUNK / 128);   // 2 groups per chunk
  const int cw  = cb + wk * 64;        // wave's first column
  const int wqw = wcb + wk * 8;        // wave's first packed word

  // group scale/zero per half: raw staging -> fp16 splat pairs
  f32x4 sra[2], srb[2]; int zrw[2];
  half2v nz[2][8], ss[2][8];
  auto load_group_raw = [&](int g) {
    #pragma unroll
    for (int h = 0; h < 2; ++h) {
      sra[h] = *(const f32x4*)(sc + g * OUT_F + cw + h * 32 + ww * 8);
      srb[h] = *(const f32x4*)(sc + g * OUT_F + cw + h * 32 + ww * 8 + 4);
      zrw[h] = qz[g * WCOLS + wqw + h * 4 + ww];
    }
  };
  auto conv_group = [&]() {
    #pragma unroll
    for (int h = 0; h < 2; ++h) {
      #pragma unroll
      for (int l = 0; l < 8; ++l) {
        const int sh = 4 * (l >> 1) + 16 * (l & 1);   // shift = 4*REV[l]
        const int zi = (zrw[h] >> sh) & 15;
        nz[h][l] = splat_h(-(float)(1024 + zi));
        ss[h][l] = splat_h((l < 4) ? sra[h][l] : srb[h][l - 4]);
      }
    }
  };
  auto load_a = [&](int t, int mf) -> half8v {
    const int m = cl + 16 * mf;
    const int k = K0 + t * 32 + q4 * 8;
    const f32x4* xp = (const f32x4*)(x + m * IN_F + k);
    f32x4 lo = xp[0], hi = xp[1];
    half8v af;
    #pragma unroll
    for (int j = 0; j < 4; ++j) {
      af[j]     = (_Float16)lo[j];
      af[4 + j] = (_Float16)hi[j];
    }
    return af;
  };
  // read (col c, kp=4q4+i) stored at c*16 + (kp ^ ((c>>3)<<2)):
  // b128 at c*16 + 4*(q4 ^ ((c>>3)&3)) -> k-contiguous 8q4..8q4+7.
  auto read_b = [&](int p, int h, int c) -> half8v {
    const int idx = c * 16 + 4 * (q4 ^ ((c >> 3) & 3));
    return __builtin_bit_cast(half8v, *(const int4v*)&lds[p][w][h][idx]);
  };

  // ---- prologue: group-0 raws, ALL q-loads (8 tiles x 2 halves) to regs.
  load_group_raw(g0);
  int qa[NTILE][2], qb[NTILE][2];
  #pragma unroll
  for (int t = 0; t < NTILE; ++t) {
    #pragma unroll
    for (int h = 0; h < 2; ++h) {
      const int r = (K0 + t * 32 + 2 * kp2) * WCOLS + wqw + h * 4 + ww;
      qa[t][h] = qw[r];
      qb[t][h] = qw[r + WCOLS];
    }
  }
  conv_group();
  f32x4 acc[2][2][2] = {};   // [mf][h][cfrag]

  // fp16 perm-dequant + LDS-write for tile t (verified R10-12):
  // per col l: v_perm gathers nibble-byte pb of (q0,q1) -> W = exact fp16
  // (1024+n) pair -> pk_add(-(1024+z)) exact (q-z) -> pk_mul by fp16 s.
  auto dq_write = [&](int t) {
    const int p = t & 1;
    #pragma unroll
    for (int h = 0; h < 2; ++h) {
      const int q0 = qa[t][h], q1 = qb[t][h];
      const int h0 = (int)((unsigned)q0 >> 4);
      const int h1 = (int)((unsigned)q1 >> 4);
      #pragma unroll
      for (int l = 0; l < 8; ++l) {
        const int pb = 2 * (l & 1) + (l >> 2);             // source byte
        const unsigned sel = (unsigned)(4 + pb) | ((unsigned)(4 + pb) << 8)
                           | ((unsigned)pb << 16) | ((unsigned)pb << 24);
        const int x0 = ((l >> 1) & 1) ? h0 : q0;
        const int x1 = ((l >> 1) & 1) ? h1 : q1;
        unsigned P = __builtin_amdgcn_perm((unsigned)x0, (unsigned)x1, sel);
        unsigned W = (P & 0x000F000Fu) | 0x64006400u;      // fp16: 1024+n
        half2v wh = (__builtin_bit_cast(half2v, W) + nz[h][l]) * ss[h][l];
        lds[p][w][h][(ww * 8 + l) * 16 + kps] = __builtin_bit_cast(int, wh);
      }
    }
  };

  // ---- pipelined main loop: write(t) while consuming (t-1)
  dq_write(0);
  half8v a0c = load_a(0, 0), a1c = load_a(0, 1);

  #pragma unroll
  for (int t = 1; t < NTILE; ++t) {
    const int pm = (t - 1) & 1;
    half8v bf00 = read_b(pm, 0, cl), bf01 = read_b(pm, 0, cl + 16);
    half8v bf10 = read_b(pm, 1, cl), bf11 = read_b(pm, 1, cl + 16);
    half8v a0n = load_a(t, 0), a1n = load_a(t, 1);
    if (t == 2) load_group_raw(g0 + 1);   // raws 2 tiles early
    if (t == 4) conv_group();             // group 1 live for tiles 4..7

    dq_write(t);                          // VALU hides the reads above

    acc[0][0][0] = mfma16h(a0c, bf00, acc[0][0][0]);
    acc[0][0][1] = mfma16h(a0c, bf01, acc[0][0][1]);
    acc[1][0][0] = mfma16h(a1c, bf00, acc[1][0][0]);
    acc[1][0][1] = mfma16h(a1c, bf01, acc[1][0][1]);
    acc[0][1][0] = mfma16h(a0c, bf10, acc[0][1][0]);
    acc[0][1][1] = mfma16h(a0c, bf11, acc[0][1][1]);
    acc[1][1][0] = mfma16h(a1c, bf10, acc[1][1][0]);
    acc[1][1][1] = mfma16h(a1c, bf11, acc[1][1][1]);

    a0c = a0n; a1c = a1n;
  }

  // ---- final tile (reads from lds[1] only: pm = 7&1 = 1)
  {
    const int pm = (NTILE - 1) & 1;
    half8v bf00 = read_b(pm, 0, cl), bf01 = read_b(pm, 0, cl + 16);
    half8v bf10 = read_b(pm, 1, cl), bf11 = read_b(pm, 1, cl + 16);
    acc[0][0][0] = mfma16h(a0c, bf00, acc[0][0][0]);
    acc[0][0][1] = mfma16h(a0c, bf01, acc[0][0][1]);
    acc[1][0][0] = mfma16h(a1c, bf00, acc[1][0][0]);
    acc[1][0][1] = mfma16h(a1c, bf01, acc[1][0][1]);
    acc[0][1][0] = mfma16h(a0c, bf10, acc[0][1][0]);
    acc[0][1][1] = mfma16h(a0c, bf11, acc[0][1][1]);
    acc[1][1][0] = mfma16h(a1c, bf10, acc[1][1][0]);
    acc[1][1][1] = mfma16h(a1c, bf11, acc[1][1][1]);
  }

  // ---- output epilogue
  const int r0 = q4 * 4;
  if constexpr (TOWS) {
    // in-block k-pair sum through lds[0] (idx-major: conflict-free,
    // no overlap with lds[1], which held the final tile)
    float* xch = (float*)&lds[0][0][0][0];   // 4096 floats = 16 KB
    const int base = wk * 64 + lane;         // 0..127
    __syncthreads();                         // all waves past main loop
    if (kh == 1) {
      #pragma unroll
      for (int mf = 0; mf < 2; ++mf)
        #pragma unroll
        for (int h = 0; h < 2; ++h)
          #pragma unroll
          for (int cf = 0; cf < 2; ++cf)
            #pragma unroll
            for (int i = 0; i < 4; ++i) {
              const int e = (((mf * 2 + h) * 2 + cf) * 4 + i);
              xch[e * 128 + base] = acc[mf][h][cf][i];
            }
    }
    __syncthreads();
    if (kh == 0) {
      unsigned short* wsp = (unsigned short*)outp + kc * SLAB;
      #pragma unroll
      for (int mf = 0; mf < 2; ++mf)
        #pragma unroll
        for (int h = 0; h < 2; ++h)
          #pragma unroll
          for (int cf = 0; cf < 2; ++cf)
            #pragma unroll
            for (int i = 0; i < 4; ++i) {
              const int e = (((mf * 2 + h) * 2 + cf) * 4 + i);
              const float sum = acc[mf][h][cf][i] + xch[e * 128 + base];
              const int row = mf * 16 + r0 + i;
              const int c0  = cw + h * 32 + cl + cf * 16;
              __builtin_nontemporal_store(f2bfu(sum), wsp + row * OUT_F + c0);
            }
    }
  } else {
    // fallback: fp32 atomics onto bias-initialized out
    float* op = (float*)outp;
    #pragma unroll
    for (int mf = 0; mf < 2; ++mf) {
      #pragma unroll
      for (int h = 0; h < 2; ++h) {
        #pragma unroll
        for (int i = 0; i < 4; ++i) {
          const int row = mf * 16 + r0 + i;
          const int c0  = cw + h * 32 + cl;
          atomicAdd(op + row * OUT_F + c0,      acc[mf][h][0][i]);
          atomicAdd(op + row * OUT_F + c0 + 16, acc[mf][h][1][i]);
        }
      }
    }
  }
}

extern "C" void kernel_launch(void* const* d_in, const int* in_sizes, int n_in,
                              void* d_out, int out_size, void* d_ws, size_t ws_size,
                              hipStream_t stream) {
  const float* x    = (const float*)d_in[0];
  const int*   qwp  = (const int*)d_in[1];
  const int*   qzp  = (const int*)d_in[2];
  const float* scp  = (const float*)d_in[3];
  const float* bias = (const float*)d_in[4];
  float* out = (float*)d_out;

  const size_t ws_slabs = (size_t)NKC * SLAB * 2;   // 5.6 MB (bf16)

  if (ws_size >= ws_slabs) {
    unsigned short* ws = (unsigned short*)d_ws;
    awq_main<true><<<NBLK, 256, 0, stream>>>(x, qwp, qzp, scp, ws);
    awq_reduce<<<SLAB / 4 / 256, 256, 0, stream>>>(ws, bias, out);
  } else {
    awq_init<<<dim3(43, 32), 256, 0, stream>>>(bias, out);
    awq_main<false><<<NBLK, 256, 0, stream>>>(x, qwp, qzp, scp, out);
  }
}